// Round 14
// baseline (167.343 us; speedup 1.0000x reference)
//
#include <hip/hip_runtime.h>
#include <math.h>

#define BATCH 32
#define HH 512
#define WW 512
#define NC 32        // cells per side
#define NORI 6
#define CH 262144    // HH*WW channel stride (floats)
#define NBLK 512     // persistent blocks: 2048 tiles / 512 = 4 tiles each

// ---- round-5-verbatim numpy downstream (cold path, ONE inline copy) ----
__device__ __forceinline__ int bin_of(float a) {
    const float deg = __fmul_rn(a, 57.29577951308232f);
    float m = fmodf(deg, 180.0f);
    if (m < 0.0f) m = __fadd_rn(m, 180.0f);
    const int b = (int)floorf(__fdiv_rn(m, 30.0f));
    return min(max(b, 0), NORI - 1);
}
__device__ __forceinline__ float ulp_step(float x, int k) {
    const int i = __float_as_int(x);
    int key = (i >= 0) ? i : -(i & 0x7FFFFFFF);
    key += k;
    const int r = (key >= 0) ? key : (int)(0x80000000u | (unsigned)(-key));
    return __int_as_float(r);
}
__device__ __forceinline__ void deposit(float acc[NORI], int bin, float val) {
#pragma unroll
    for (int o = 0; o < NORI; ++o) acc[o] += (bin == o) ? val : 0.0f;
}
// (0.299*R + 0.587*G) + 0.114*B, f32, no FMA contraction
__device__ __forceinline__ float gray_comb(float r, float g, float b) {
    return __fadd_rn(__fadd_rn(__fmul_rn(0.299f, r), __fmul_rn(0.587f, g)),
                     __fmul_rn(0.114f, b));
}
__device__ __forceinline__ float gray_i(const float* __restrict__ img, int off) {
    return gray_comb(img[off], img[off + CH], img[off + 2 * CH]);
}

__device__ __forceinline__ void hot_pixel(float gy, float gx, int bitk,
                                          float acc[NORI], unsigned& ambmask) {
    const float mag = __fsqrt_rn(__fmaf_rn(gy, gy, __fmul_rn(gx, gx)));
    const bool neg = gy < 0.0f;
    const float cy = fabsf(gy);
    const float cx = neg ? -gx : gx;
    const float pa = __fmul_rn(cy, 0.86602540378443864676f);
    const float pb = __fmul_rn(cx, 0.5f);
    const float pc = __fmul_rn(cy, 0.5f);
    const float pd = __fmul_rn(cx, 0.86602540378443864676f);
    const float t1 = __fsub_rn(pa, pb);
    const float t2 = __fsub_rn(pc, pd);
    const float t3 = -cx;
    const float t4 = -__fadd_rn(pc, pd);
    const float t5 = -__fadd_rn(pa, pb);
    int bin = (t1 >= 0.0f) + (t2 >= 0.0f) + (t3 >= 0.0f) +
              (t4 >= 0.0f) + (t5 >= 0.0f);
    const float s = __fmul_rn(mag, 1e-5f);
    const float mn = fminf(fminf(fminf(fabsf(t1), fabsf(t2)),
                                 fminf(fabsf(t3), fabsf(t4))), fabsf(t5));
    bool amb = (mn < s) || (cx < 0.0f && cy < s);   // incl. wrap at 180
    if (gy == 0.0f) { bin = 0; amb = false; }       // deterministic (r3/r5)
    else if (gx == 0.0f) { bin = 3; amb = false; }
    ambmask |= amb ? (1u << bitk) : 0u;
    deposit(acc, bin, amb ? 0.0f : mag);
}

struct TileRegs {
    float4 cr[6], cg[6], cb[6];   // raw channels, rows R0-1..R0+4
    float hr[6], hg[6], hb[6];    // halo column (edge lanes only)
};

__device__ __forceinline__ void load_tile(const float* __restrict__ x,
                                          int b, int by, int wave,
                                          int c0, int hc, bool is_h,
                                          TileRegs& T) {
    const float* img = x + (size_t)b * 3 * CH;
    const int R0 = by * 16 + wave * 4;
#pragma unroll
    for (int i = 0; i < 6; ++i) {
        const int roff = min(max(R0 - 1 + i, 0), HH - 1) * WW;
        T.cr[i] = *(const float4*)(img + roff + c0);
        T.cg[i] = *(const float4*)(img + roff + c0 + CH);
        T.cb[i] = *(const float4*)(img + roff + c0 + 2 * CH);
        T.hr[i] = is_h ? img[roff + hc] : 0.0f;
        T.hg[i] = is_h ? img[roff + hc + CH] : 0.0f;
        T.hb[i] = is_h ? img[roff + hc + 2 * CH] : 0.0f;
    }
}

// Persistent software-pipelined cells kernel. 512 blocks x 4 tiles; while one
// tile is classified (~1500 cyc VALU), the next tile's 18 dwordx4 burst is in
// flight -- steady-state latency overlap every iteration (the piece all the
// one-shot variants r6-r13 lacked). Wave-independent epilogue (r13 partials).
__global__ __launch_bounds__(256) void hog_cells_kernel(const float* __restrict__ x,
                                                        float* __restrict__ part) {
    const int tid = threadIdx.x;
    const int wave = tid >> 6, lane = tid & 63;
    const int t0 = blockIdx.x;
    const int bx = t0 & 1;                  // block-constant (stride 512 even)
    const bool left_blk = (bx == 0);
    const int hc = left_blk ? 256 : 255;
    const bool is_h = (lane == (left_blk ? 63 : 0));
    const int c0 = bx * 256 + lane * 4;

    TileRegs A, B;
    int t = t0;
    int b = t >> 6, by = (t >> 1) & 31;
    load_tile(x, b, by, wave, c0, hc, is_h, A);

#pragma unroll
    for (int i = 0; i < 4; ++i) {
        // ---- grayify A (waits its loads; frees 90 raw regs -> 30 gray) ----
        float4 g[6];
        float hgray[6];
#pragma unroll
        for (int j = 0; j < 6; ++j) {
            g[j].x = gray_comb(A.cr[j].x, A.cg[j].x, A.cb[j].x);
            g[j].y = gray_comb(A.cr[j].y, A.cg[j].y, A.cb[j].y);
            g[j].z = gray_comb(A.cr[j].z, A.cg[j].z, A.cb[j].z);
            g[j].w = gray_comb(A.cr[j].w, A.cg[j].w, A.cb[j].w);
            hgray[j] = gray_comb(A.hr[j], A.hg[j], A.hb[j]);
        }

        // ---- prefetch next tile: burst in flight during classify ----
        const int tn = t + NBLK;
        const int bn = tn >> 6, byn = (tn >> 1) & 31;
        if (i < 3) load_tile(x, bn, byn, wave, c0, hc, is_h, B);

        // ---- classify tile (r13-verbatim) ----
        const int R0 = by * 16 + wave * 4;
        const float* img = x + (size_t)b * 3 * CH;
        float acc[NORI] = {0, 0, 0, 0, 0, 0};
        unsigned ambmask = 0;
#pragma unroll
        for (int k = 0; k < 4; ++k) {
            const int r = R0 + k;
            const bool row_ok = (r >= 1) && (r < HH - 1);
            const float4 gt = g[k], gc = g[k + 1], gb = g[k + 2];
            const float gy0 = row_ok ? __fsub_rn(gb.x, gt.x) : 0.0f;
            const float gy1 = row_ok ? __fsub_rn(gb.y, gt.y) : 0.0f;
            const float gy2 = row_ok ? __fsub_rn(gb.z, gt.z) : 0.0f;
            const float gy3 = row_ok ? __fsub_rn(gb.w, gt.w) : 0.0f;

            float left  = __shfl(gc.w, (lane + 63) & 63);
            float right = __shfl(gc.x, (lane + 1) & 63);
            if (is_h) { if (left_blk) right = hgray[k + 1]; else left = hgray[k + 1]; }

            float gx0 = __fsub_rn(gc.y, left);
            const float gx1 = __fsub_rn(gc.z, gc.x);
            const float gx2 = __fsub_rn(gc.w, gc.y);
            float gx3 = __fsub_rn(right, gc.z);
            if (c0 == 0) gx0 = 0.0f;             // image left border
            if (c0 + 3 == WW - 1) gx3 = 0.0f;    // image right border

            hot_pixel(gy0, gx0, 4 * k + 0, acc, ambmask);
            hot_pixel(gy1, gx1, 4 * k + 1, acc, ambmask);
            hot_pixel(gy2, gx2, 4 * k + 2, acc, ambmask);
            hot_pixel(gy3, gx3, 4 * k + 3, acc, ambmask);
        }

        // cold phase: rare; re-read global, bitwise identical (r5 policy)
        if (__any(ambmask != 0)) {
            unsigned m = ambmask;
            while (m) {
                const int bit = __builtin_ctz(m);
                m &= m - 1;
                const int r = R0 + (bit >> 2);
                const int c = c0 + (bit & 3);
                const int off = r * WW + c;
                const float gy = __fsub_rn(gray_i(img, off + WW), gray_i(img, off - WW));
                const float gx = __fsub_rn(gray_i(img, off + 1), gray_i(img, off - 1));
                const float mag = __fsqrt_rn(__fmaf_rn(gy, gy, __fmul_rn(gx, gx)));
                const float a = atan2f(gy, gx);
                const int bl = bin_of(ulp_step(a, -2));
                const int bh = bin_of(ulp_step(a, +2));
                if (bl == bh) {
                    deposit(acc, bl, mag);
                } else {
                    const int b0 = bin_of(a);
                    const int bo = (b0 == bl) ? bh : bl;
                    deposit(acc, b0, __fmul_rn(mag, 0.65f));
                    deposit(acc, bo, __fmul_rn(mag, 0.35f));
                }
            }
        }

        // reduce the 4 lanes of each cell, write per-subrow partials
#pragma unroll
        for (int o = 0; o < NORI; ++o) {
            float v = acc[o];
            v += __shfl_xor(v, 1);
            v += __shfl_xor(v, 2);
            acc[o] = v;
        }
        if ((lane & 3) == 0) {
            const int cc = bx * 16 + (lane >> 2);
            float* pp = part + ((((size_t)b * NC + by) * NC + cc) * 4 + wave) * NORI;
#pragma unroll
            for (int o = 0; o < NORI; ++o) pp[o] = acc[o];
        }

        if (i < 3) { A = B; t = tn; b = bn; by = byn; }
    }
}

// One thread per (b, block_row, block_col): sum 4 subrow partials per cell,
// then L2-Hys normalize. (r13-verbatim)
__global__ __launch_bounds__(256) void hog_norm_kernel(const float* __restrict__ part,
                                                       float* __restrict__ out) {
    const int idx = blockIdx.x * 256 + threadIdx.x;
    const int total = BATCH * 31 * 31;
    if (idx >= total) return;
    const int bc = idx % 31;
    const int t = idx / 31;
    const int br = t % 31;
    const int b = t / 31;

    float v[24];
#pragma unroll
    for (int i = 0; i < 2; ++i)
#pragma unroll
        for (int j = 0; j < 2; ++j) {
            const float* pp = part + ((((size_t)b * NC + (br + i)) * NC + (bc + j)) * 4) * NORI;
            float s[NORI];
#pragma unroll
            for (int o = 0; o < NORI; ++o)
                s[o] = ((pp[o] + pp[6 + o]) + pp[12 + o]) + pp[18 + o];
#pragma unroll
            for (int o = 0; o < NORI; ++o)
                v[(i * 2 + j) * NORI + o] = s[o] * (1.0f / 256.0f);
        }

    float ss = 0.0f;
#pragma unroll
    for (int k = 0; k < 24; ++k) ss = __fadd_rn(ss, __fmul_rn(v[k], v[k]));
    const float n1 = __fsqrt_rn(__fadd_rn(ss, 1e-10f));  // EPS^2, EPS=1e-5
    float ss2 = 0.0f;
#pragma unroll
    for (int k = 0; k < 24; ++k) {
        v[k] = fminf(__fdiv_rn(v[k], n1), 0.2f);
        ss2 = __fadd_rn(ss2, __fmul_rn(v[k], v[k]));
    }
    const float n2 = __fsqrt_rn(__fadd_rn(ss2, 1e-10f));
    float* op = out + (size_t)idx * 24;
#pragma unroll
    for (int k = 0; k < 24; ++k) op[k] = __fdiv_rn(v[k], n2);
}

extern "C" void kernel_launch(void* const* d_in, const int* in_sizes, int n_in,
                              void* d_out, int out_size, void* d_ws, size_t ws_size,
                              hipStream_t stream) {
    const float* x = (const float*)d_in[0];
    float* out = (float*)d_out;
    float* part = (float*)d_ws;   // BATCH*32*32*4*6 floats = 12 MB

    hog_cells_kernel<<<NBLK, 256, 0, stream>>>(x, part);

    const int total = BATCH * 31 * 31;
    hog_norm_kernel<<<(total + 255) / 256, 256, 0, stream>>>(part, out);
}